// Round 4
// baseline (383.680 us; speedup 1.0000x reference)
//
#include <hip/hip_runtime.h>

#define EMBD 32
#define KN 10

__device__ __forceinline__ float bf_lo(unsigned int u){ union{unsigned int v; float f;}c; c.v = u<<16; return c.f; }
__device__ __forceinline__ float bf_hi(unsigned int u){ union{unsigned int v; float f;}c; c.v = u & 0xFFFF0000u; return c.f; }
__device__ __forceinline__ unsigned short f2bf(float f){
    union{float f; unsigned int u;}c; c.f=f;
    unsigned int r = c.u + 0x7FFFu + ((c.u>>16)&1u);   // RNE
    return (unsigned short)(r>>16);
}
// nontemporal 8 B load of 4 bf16 -> 4 floats (scalar u64: vector types rejected)
__device__ __forceinline__ void ld_nt4bf(const unsigned short* p,
                                         float& f0, float& f1, float& f2, float& f3){
    unsigned long long v = __builtin_nontemporal_load((const unsigned long long*)p);
    unsigned int lo = (unsigned int)v, hi = (unsigned int)(v >> 32);
    f0 = bf_lo(lo); f1 = bf_hi(lo); f2 = bf_lo(hi); f3 = bf_hi(hi);
}

// streaming f32 -> bf16 for the neighbor-gather table (~96 MB traffic)
__global__ __launch_bounds__(256)
void cvt_bf16(const float4* __restrict__ in, ushort4* __restrict__ out, int n4){
    int i = blockIdx.x*256 + threadIdx.x;
    if (i < n4){
        float4 v = in[i];
        ushort4 o; o.x=f2bf(v.x); o.y=f2bf(v.y); o.z=f2bf(v.z); o.w=f2bf(v.w);
        out[i]=o;
    }
}

// Layer 1: 64 rows/block (rows == node ids). Neighbor indices staged to LDS
// (coalesced), gathers are 8 B/lane -> 8 rows per VMEM inst, nontemporal.
// Self term read as f32 stream in the compute phase (no LDS round-trip).
__global__ __launch_bounds__(256, 6)
void sage_l1(const float* __restrict__ emb,            // f32 [N,32]
             const unsigned short* __restrict__ embb,  // bf16 [N,32]
             const float* __restrict__ W,              // f32 [32][64]
             const int* __restrict__ neigh,            // [N,10]
             unsigned short* __restrict__ h1,          // bf16 out [N,32]
             int n_rows)
{
    __shared__ __align__(16) int sidx[64*KN];
    __shared__ float sagg[64][33];                     // [row][aggdim]
    const int tid  = threadIdx.x;
    const int row0 = blockIdx.x << 6;

    if (row0 + 64 <= n_rows) {                         // contiguous 2.5 KB of neigh
        if (tid < 160)
            ((int4*)sidx)[tid] = ((const int4*)(neigh + (size_t)row0*KN))[tid];
    } else {                                           // tail: guarded, OOB rows -> node 0
        for (int t = tid; t < 64*KN; t += 256) {
            int lr = t / KN;
            sidx[t] = (row0 + lr < n_rows) ? neigh[(size_t)row0*KN + t] : 0;
        }
    }
    __syncthreads();

    const int lane = tid & 63;
    const int wv   = tid >> 6;
    const int slot = lane & 7;      // 8-byte slot within a 64 B row
    const int rsub = lane >> 3;     // row within group of 8

    #pragma unroll
    for (int gi = 0; gi < 2; ++gi) {
        const int row = (2*wv + gi)*8 + rsub;
        float a0=0.f,a1=0.f,a2=0.f,a3=0.f;
        #pragma unroll
        for (int k = 0; k < KN; ++k) {
            const int idx = sidx[row*KN + k];          // LDS, 8 distinct banks + broadcast
            float f0,f1,f2,f3;
            ld_nt4bf(embb + (size_t)idx*EMBD + slot*4, f0,f1,f2,f3);
            a0 += f0; a1 += f1; a2 += f2; a3 += f3;
        }
        sagg[row][slot*4+0] = a0*0.1f;
        sagg[row][slot*4+1] = a1*0.1f;
        sagg[row][slot*4+2] = a2*0.1f;
        sagg[row][slot*4+3] = a3*0.1f;
    }
    __syncthreads();

    // compute: thread = (row=lane, outputs 8*wv..8*wv+8)
    const int row = lane;
    const int r   = row0 + row;
    const int rc  = (r < n_rows) ? r : (n_rows - 1);
    const float* selfrow = emb + (size_t)rc * EMBD;    // f32 stream, lane==row -> coalesced
    const float* Wb = W + wv*8*64;                     // wave-uniform -> s_load

    float acc[8] = {0,0,0,0,0,0,0,0};
    #pragma unroll
    for (int c4 = 0; c4 < 8; ++c4) {                   // self half (dims 0..31)
        const float4 s = ((const float4*)selfrow)[c4];
        #pragma unroll
        for (int q = 0; q < 8; ++q) {
            acc[q] = fmaf(s.x, Wb[q*64 + c4*4 + 0], acc[q]);
            acc[q] = fmaf(s.y, Wb[q*64 + c4*4 + 1], acc[q]);
            acc[q] = fmaf(s.z, Wb[q*64 + c4*4 + 2], acc[q]);
            acc[q] = fmaf(s.w, Wb[q*64 + c4*4 + 3], acc[q]);
        }
    }
    #pragma unroll 8
    for (int j = 0; j < 32; ++j) {                     // agg half (dims 32..63)
        const float c = sagg[row][j];
        #pragma unroll
        for (int q = 0; q < 8; ++q)
            acc[q] = fmaf(c, Wb[q*64 + 32 + j], acc[q]);
    }
    if (r < n_rows) {
        unsigned int pk[4];
        #pragma unroll
        for (int q = 0; q < 4; ++q) {
            float x0 = fmaxf(acc[2*q],0.f), x1 = fmaxf(acc[2*q+1],0.f);
            pk[q] = (unsigned int)f2bf(x0) | ((unsigned int)f2bf(x1)<<16);
        }
        *(uint4*)(h1 + (size_t)r*EMBD + wv*8) = make_uint4(pk[0],pk[1],pk[2],pk[3]);
    }
}

// Layer 2: indices fully staged to LDS first (breaks the remap->neigh->gather
// latency chain), then the same 8-rows-per-inst gather for self + neighbors.
__global__ __launch_bounds__(256, 6)
void sage_l2(const unsigned short* __restrict__ h1,   // bf16 [N,32]
             const float* __restrict__ W,             // f32 [32][64]
             const int* __restrict__ neigh,           // [N,10]
             const int* __restrict__ batch,           // [B]
             float* __restrict__ out,                 // f32 [B,32]
             int n_rows)
{
    __shared__ int snode[64];
    __shared__ __align__(16) int sidx[64*KN];
    __shared__ float sh[64][67];                      // [row][dim]
    const int tid  = threadIdx.x;
    const int row0 = blockIdx.x << 6;

    if (tid < 64) {
        int r = row0 + tid;
        snode[tid] = (r < n_rows) ? batch[r] : 0;     // coalesced, 1 inst
    }
    __syncthreads();
    for (int t = tid; t < 64*KN; t += 256) {          // 640 idx, ~64 lines, 10 wave-insts
        int lr = t / KN;
        int k  = t - lr*KN;
        sidx[t] = neigh[(size_t)snode[lr]*KN + k];
    }
    __syncthreads();

    const int lane = tid & 63;
    const int wv   = tid >> 6;
    const int slot = lane & 7;
    const int rsub = lane >> 3;

    #pragma unroll
    for (int gi = 0; gi < 2; ++gi) {
        const int row = (2*wv + gi)*8 + rsub;
        {   // self (random node -> gather)
            const int node = snode[row];
            float f0,f1,f2,f3;
            ld_nt4bf(h1 + (size_t)node*EMBD + slot*4, f0,f1,f2,f3);
            sh[row][slot*4+0] = f0;
            sh[row][slot*4+1] = f1;
            sh[row][slot*4+2] = f2;
            sh[row][slot*4+3] = f3;
        }
        float a0=0.f,a1=0.f,a2=0.f,a3=0.f;
        #pragma unroll
        for (int k = 0; k < KN; ++k) {
            const int idx = sidx[row*KN + k];
            float f0,f1,f2,f3;
            ld_nt4bf(h1 + (size_t)idx*EMBD + slot*4, f0,f1,f2,f3);
            a0 += f0; a1 += f1; a2 += f2; a3 += f3;
        }
        sh[row][32 + slot*4+0] = a0*0.1f;
        sh[row][32 + slot*4+1] = a1*0.1f;
        sh[row][32 + slot*4+2] = a2*0.1f;
        sh[row][32 + slot*4+3] = a3*0.1f;
    }
    __syncthreads();

    const int row = lane;
    const int r   = row0 + row;
    const float* Wb = W + wv*8*64;                    // wave-uniform
    float acc[8] = {0,0,0,0,0,0,0,0};
    #pragma unroll 8
    for (int j = 0; j < 64; ++j) {
        const float c = sh[row][j];
        #pragma unroll
        for (int q = 0; q < 8; ++q)
            acc[q] = fmaf(c, Wb[q*64 + j], acc[q]);
    }
    if (r < n_rows) {
        float* dst = out + (size_t)r*EMBD + wv*8;
        ((float4*)dst)[0] = make_float4(fmaxf(acc[0],0.f),fmaxf(acc[1],0.f),
                                        fmaxf(acc[2],0.f),fmaxf(acc[3],0.f));
        ((float4*)dst)[1] = make_float4(fmaxf(acc[4],0.f),fmaxf(acc[5],0.f),
                                        fmaxf(acc[6],0.f),fmaxf(acc[7],0.f));
    }
}

extern "C" void kernel_launch(void* const* d_in, const int* in_sizes, int n_in,
                              void* d_out, int out_size, void* d_ws, size_t ws_size,
                              hipStream_t stream)
{
    // dict order: emb [N,32] f32, W1 [32,64] f32, W2 [32,64] f32,
    //             node_batch [B] i32, neigh [N,10] i32
    const float* emb        = (const float*)d_in[0];
    const float* W1         = (const float*)d_in[1];
    const float* W2         = (const float*)d_in[2];
    const int*   node_batch = (const int*)  d_in[3];
    const int*   neigh      = (const int*)  d_in[4];

    const int N = in_sizes[0] / EMBD;   // 500000
    const int B = in_sizes[3];          // 100000

    unsigned short* emb_bf = (unsigned short*)d_ws;              // 32 MB
    unsigned short* h1_bf  = emb_bf + (size_t)N * EMBD;          // 32 MB

    const int n4 = (N * EMBD) / 4;
    cvt_bf16<<<(n4 + 255) / 256, 256, 0, stream>>>(
        (const float4*)emb, (ushort4*)emb_bf, n4);

    sage_l1<<<(N + 63) / 64, 256, 0, stream>>>(
        emb, emb_bf, W1, neigh, h1_bf, N);

    sage_l2<<<(B + 63) / 64, 256, 0, stream>>>(
        h1_bf, W2, neigh, node_batch, (float*)d_out, B);
}

// Round 5
// 330.684 us; speedup vs baseline: 1.1603x; 1.1603x over previous
//
#include <hip/hip_runtime.h>

#define EMBD 32
#define KN 10

__device__ __forceinline__ float bf_lo(unsigned int u){ union{unsigned int v; float f;}c; c.v = u<<16; return c.f; }
__device__ __forceinline__ float bf_hi(unsigned int u){ union{unsigned int v; float f;}c; c.v = u & 0xFFFF0000u; return c.f; }
__device__ __forceinline__ unsigned short f2bf(float f){
    union{float f; unsigned int u;}c; c.f=f;
    unsigned int r = c.u + 0x7FFFu + ((c.u>>16)&1u);   // RNE
    return (unsigned short)(r>>16);
}
// plain (cached) 8 B load of 4 bf16 -> 4 floats. NO nontemporal: gather rows
// have ~10x average reuse (R4 post-mortem: nt cost 2.3x on L1).
__device__ __forceinline__ void ld4bf(const unsigned short* p,
                                      float& f0, float& f1, float& f2, float& f3){
    unsigned long long v = *(const unsigned long long*)p;
    unsigned int lo = (unsigned int)v, hi = (unsigned int)(v >> 32);
    f0 = bf_lo(lo); f1 = bf_hi(lo); f2 = bf_lo(hi); f3 = bf_hi(hi);
}

// streaming f32 -> bf16 for the neighbor-gather table (~96 MB traffic)
__global__ __launch_bounds__(256)
void cvt_bf16(const float4* __restrict__ in, ushort4* __restrict__ out, int n4){
    int i = blockIdx.x*256 + threadIdx.x;
    if (i < n4){
        float4 v = in[i];
        ushort4 o; o.x=f2bf(v.x); o.y=f2bf(v.y); o.z=f2bf(v.z); o.w=f2bf(v.w);
        out[i]=o;
    }
}

// Layer 1: 64 rows/block (rows == node ids). Neighbor indices staged to LDS
// (coalesced), gathers are 8 B/lane -> 8 rows per VMEM inst (cached).
// Self term read as f32 stream in the compute phase (no LDS round-trip).
__global__ __launch_bounds__(256, 6)
void sage_l1(const float* __restrict__ emb,            // f32 [N,32]
             const unsigned short* __restrict__ embb,  // bf16 [N,32]
             const float* __restrict__ W,              // f32 [32][64]
             const int* __restrict__ neigh,            // [N,10]
             unsigned short* __restrict__ h1,          // bf16 out [N,32]
             int n_rows)
{
    __shared__ __align__(16) int sidx[64*KN];
    __shared__ float sagg[64][33];                     // [row][aggdim]
    const int tid  = threadIdx.x;
    const int row0 = blockIdx.x << 6;

    if (row0 + 64 <= n_rows) {                         // contiguous 2.5 KB of neigh
        if (tid < 160)
            ((int4*)sidx)[tid] = ((const int4*)(neigh + (size_t)row0*KN))[tid];
    } else {                                           // tail: guarded, OOB rows -> node 0
        for (int t = tid; t < 64*KN; t += 256) {
            int lr = t / KN;
            sidx[t] = (row0 + lr < n_rows) ? neigh[(size_t)row0*KN + t] : 0;
        }
    }
    __syncthreads();

    const int lane = tid & 63;
    const int wv   = tid >> 6;
    const int slot = lane & 7;      // 8-byte slot within a 64 B row
    const int rsub = lane >> 3;     // row within group of 8

    #pragma unroll
    for (int gi = 0; gi < 2; ++gi) {
        const int row = (2*wv + gi)*8 + rsub;
        float a0=0.f,a1=0.f,a2=0.f,a3=0.f;
        #pragma unroll
        for (int k = 0; k < KN; ++k) {
            const int idx = sidx[row*KN + k];          // LDS, 8 distinct banks + broadcast
            float f0,f1,f2,f3;
            ld4bf(embb + (size_t)idx*EMBD + slot*4, f0,f1,f2,f3);
            a0 += f0; a1 += f1; a2 += f2; a3 += f3;
        }
        sagg[row][slot*4+0] = a0*0.1f;
        sagg[row][slot*4+1] = a1*0.1f;
        sagg[row][slot*4+2] = a2*0.1f;
        sagg[row][slot*4+3] = a3*0.1f;
    }
    __syncthreads();

    // compute: thread = (row=lane, outputs 8*wv..8*wv+8)
    const int row = lane;
    const int r   = row0 + row;
    const int rc  = (r < n_rows) ? r : (n_rows - 1);
    const float* selfrow = emb + (size_t)rc * EMBD;    // f32 stream, lane==row -> coalesced
    const float* Wb = W + wv*8*64;                     // wave-uniform -> s_load

    float acc[8] = {0,0,0,0,0,0,0,0};
    #pragma unroll
    for (int c4 = 0; c4 < 8; ++c4) {                   // self half (dims 0..31)
        const float4 s = ((const float4*)selfrow)[c4];
        #pragma unroll
        for (int q = 0; q < 8; ++q) {
            acc[q] = fmaf(s.x, Wb[q*64 + c4*4 + 0], acc[q]);
            acc[q] = fmaf(s.y, Wb[q*64 + c4*4 + 1], acc[q]);
            acc[q] = fmaf(s.z, Wb[q*64 + c4*4 + 2], acc[q]);
            acc[q] = fmaf(s.w, Wb[q*64 + c4*4 + 3], acc[q]);
        }
    }
    #pragma unroll 8
    for (int j = 0; j < 32; ++j) {                     // agg half (dims 32..63)
        const float c = sagg[row][j];
        #pragma unroll
        for (int q = 0; q < 8; ++q)
            acc[q] = fmaf(c, Wb[q*64 + 32 + j], acc[q]);
    }
    if (r < n_rows) {
        unsigned int pk[4];
        #pragma unroll
        for (int q = 0; q < 4; ++q) {
            float x0 = fmaxf(acc[2*q],0.f), x1 = fmaxf(acc[2*q+1],0.f);
            pk[q] = (unsigned int)f2bf(x0) | ((unsigned int)f2bf(x1)<<16);
        }
        *(uint4*)(h1 + (size_t)r*EMBD + wv*8) = make_uint4(pk[0],pk[1],pk[2],pk[3]);
    }
}

// Layer 2: indices fully staged to LDS first (breaks the remap->neigh->gather
// latency chain), then the same 8-rows-per-inst gather for self + neighbors.
__global__ __launch_bounds__(256, 6)
void sage_l2(const unsigned short* __restrict__ h1,   // bf16 [N,32]
             const float* __restrict__ W,             // f32 [32][64]
             const int* __restrict__ neigh,           // [N,10]
             const int* __restrict__ batch,           // [B]
             float* __restrict__ out,                 // f32 [B,32]
             int n_rows)
{
    __shared__ int snode[64];
    __shared__ __align__(16) int sidx[64*KN];
    __shared__ float sh[64][67];                      // [row][dim]
    const int tid  = threadIdx.x;
    const int row0 = blockIdx.x << 6;

    if (tid < 64) {
        int r = row0 + tid;
        snode[tid] = (r < n_rows) ? batch[r] : 0;     // coalesced, 1 inst
    }
    __syncthreads();
    for (int t = tid; t < 64*KN; t += 256) {          // 640 idx, ~64 lines, 10 wave-insts
        int lr = t / KN;
        int k  = t - lr*KN;
        sidx[t] = neigh[(size_t)snode[lr]*KN + k];
    }
    __syncthreads();

    const int lane = tid & 63;
    const int wv   = tid >> 6;
    const int slot = lane & 7;
    const int rsub = lane >> 3;

    #pragma unroll
    for (int gi = 0; gi < 2; ++gi) {
        const int row = (2*wv + gi)*8 + rsub;
        {   // self (random node -> gather)
            const int node = snode[row];
            float f0,f1,f2,f3;
            ld4bf(h1 + (size_t)node*EMBD + slot*4, f0,f1,f2,f3);
            sh[row][slot*4+0] = f0;
            sh[row][slot*4+1] = f1;
            sh[row][slot*4+2] = f2;
            sh[row][slot*4+3] = f3;
        }
        float a0=0.f,a1=0.f,a2=0.f,a3=0.f;
        #pragma unroll
        for (int k = 0; k < KN; ++k) {
            const int idx = sidx[row*KN + k];
            float f0,f1,f2,f3;
            ld4bf(h1 + (size_t)idx*EMBD + slot*4, f0,f1,f2,f3);
            a0 += f0; a1 += f1; a2 += f2; a3 += f3;
        }
        sh[row][32 + slot*4+0] = a0*0.1f;
        sh[row][32 + slot*4+1] = a1*0.1f;
        sh[row][32 + slot*4+2] = a2*0.1f;
        sh[row][32 + slot*4+3] = a3*0.1f;
    }
    __syncthreads();

    const int row = lane;
    const int r   = row0 + row;
    const float* Wb = W + wv*8*64;                    // wave-uniform
    float acc[8] = {0,0,0,0,0,0,0,0};
    #pragma unroll 8
    for (int j = 0; j < 64; ++j) {
        const float c = sh[row][j];
        #pragma unroll
        for (int q = 0; q < 8; ++q)
            acc[q] = fmaf(c, Wb[q*64 + j], acc[q]);
    }
    if (r < n_rows) {
        float* dst = out + (size_t)r*EMBD + wv*8;
        ((float4*)dst)[0] = make_float4(fmaxf(acc[0],0.f),fmaxf(acc[1],0.f),
                                        fmaxf(acc[2],0.f),fmaxf(acc[3],0.f));
        ((float4*)dst)[1] = make_float4(fmaxf(acc[4],0.f),fmaxf(acc[5],0.f),
                                        fmaxf(acc[6],0.f),fmaxf(acc[7],0.f));
    }
}

extern "C" void kernel_launch(void* const* d_in, const int* in_sizes, int n_in,
                              void* d_out, int out_size, void* d_ws, size_t ws_size,
                              hipStream_t stream)
{
    // dict order: emb [N,32] f32, W1 [32,64] f32, W2 [32,64] f32,
    //             node_batch [B] i32, neigh [N,10] i32
    const float* emb        = (const float*)d_in[0];
    const float* W1         = (const float*)d_in[1];
    const float* W2         = (const float*)d_in[2];
    const int*   node_batch = (const int*)  d_in[3];
    const int*   neigh      = (const int*)  d_in[4];

    const int N = in_sizes[0] / EMBD;   // 500000
    const int B = in_sizes[3];          // 100000

    unsigned short* emb_bf = (unsigned short*)d_ws;              // 32 MB
    unsigned short* h1_bf  = emb_bf + (size_t)N * EMBD;          // 32 MB

    const int n4 = (N * EMBD) / 4;
    cvt_bf16<<<(n4 + 255) / 256, 256, 0, stream>>>(
        (const float4*)emb, (ushort4*)emb_bf, n4);

    sage_l1<<<(N + 63) / 64, 256, 0, stream>>>(
        emb, emb_bf, W1, neigh, h1_bf, N);

    sage_l2<<<(B + 63) / 64, 256, 0, stream>>>(
        h1_bf, W2, neigh, node_batch, (float*)d_out, B);
}